// Round 11
// baseline (228.561 us; speedup 1.0000x reference)
//
#include <hip/hip_runtime.h>
#include <hip/hip_fp16.h>
#include <math.h>

// GAE: 2x GCNConv + edge dot decode.
// R1: bucketed CSR build, fp16 gather tables.   R2: wide gathers.
// R3-R5: unrolled gathers, fixed-capacity buckets.
// R6: fp16 packed accumulation, zero-pad row, bf16 decode.
// R7: 1 node/wave peeled gathers.  R8: mm1/mm2 as MFMA.
// R9: 2 nodes/wave halves.  R10: 4 nodes/wave quarters.
// R11: decode 2 lanes/edge (100k->50k waves, same law as R9/R10);
//      bfill scan via __shfl_up (18 barriers -> 1); row{beg,end} packed int2.

#define NBMAX 256    // max buckets (supports N <= 131072)
#define BSHIFT 9     // 512 nodes per bucket
#define BNODES 512
#define CH 4096      // edges per partition block
#define CAPSHIFT 14  // 16384 edge slots per bucket (mean 8192 at N=100k,E=1.6M)
#define CAP (1 << CAPSHIFT)

typedef _Float16 half8 __attribute__((ext_vector_type(8)));
typedef float floatx4 __attribute__((ext_vector_type(4)));

static inline int divup(int a, int b) { return (a + b - 1) / b; }

__device__ inline void acc8(__half2* a, float4 v) {
    const __half2* h = (const __half2*)&v;
    a[0] = __hadd2(a[0], h[0]);
    a[1] = __hadd2(a[1], h[1]);
    a[2] = __hadd2(a[2], h[2]);
    a[3] = __hadd2(a[3], h[3]);
}
__device__ inline unsigned short f2bf(float f) {
    unsigned u = __builtin_bit_cast(unsigned, f);
    u = (u + 0x7FFFu + ((u >> 16) & 1u)) >> 16;
    return (unsigned short)u;
}

// ---- init bucket cursors + zero pad rows ------------------------------------

__global__ void k_init(int* __restrict__ gcur, unsigned* __restrict__ hs_pad,
                       unsigned* __restrict__ zs_pad) {
    int t = threadIdx.x;
    if (t < NBMAX) gcur[t] = t << CAPSHIFT;
    if (t < 32) hs_pad[t] = 0;            // 128B zero row (64 fp16)
    else if (t < 48) zs_pad[t - 32] = 0;  // 64B zero row (32 fp16)
}

// ---- partition edges into fixed-capacity buckets (atomic append) ------------
// packed word: (local_tgt << 23) | src   (src < 2^17, local_tgt < 512)

__global__ __launch_bounds__(256) void k_part(const int* __restrict__ src,
                                              const int* __restrict__ tgt,
                                              int* __restrict__ gcur,
                                              unsigned* __restrict__ ebuf, int E, int NB) {
    __shared__ int h[NBMAX];
    __shared__ int base[NBMAX];
    int tid = threadIdx.x;
    int e0 = blockIdx.x * CH;
    for (int b = tid; b < NB; b += 256) h[b] = 0;
    __syncthreads();
    unsigned pk[16];
    int sv[16];
#pragma unroll
    for (int r = 0; r < 4; r++) {
        int e = e0 + (r * 256 + tid) * 4;
        if (e + 3 < E) {
            int4 t4 = *(const int4*)(tgt + e);
            int4 s4 = *(const int4*)(src + e);
            int tv[4] = {t4.x, t4.y, t4.z, t4.w};
            int sw[4] = {s4.x, s4.y, s4.z, s4.w};
#pragma unroll
            for (int j = 0; j < 4; j++) {
                int t = tv[j];
                int b = t >> BSHIFT;
                int l = atomicAdd(&h[b], 1);
                pk[r * 4 + j] = ((unsigned)b << 21) |
                                ((unsigned)(t & (BNODES - 1)) << 12) | (unsigned)l;
                sv[r * 4 + j] = sw[j];
            }
        } else {
#pragma unroll
            for (int j = 0; j < 4; j++) {
                int ee = e + j;
                if (ee < E) {
                    int t = tgt[ee];
                    int b = t >> BSHIFT;
                    int l = atomicAdd(&h[b], 1);
                    pk[r * 4 + j] = ((unsigned)b << 21) |
                                    ((unsigned)(t & (BNODES - 1)) << 12) | (unsigned)l;
                    sv[r * 4 + j] = src[ee];
                } else {
                    pk[r * 4 + j] = 0xFFFFFFFFu;
                }
            }
        }
    }
    __syncthreads();
    for (int b = tid; b < NB; b += 256) {
        int c = h[b];
        base[b] = c ? atomicAdd(&gcur[b], c) : 0;
    }
    __syncthreads();
#pragma unroll
    for (int i = 0; i < 16; i++) {
        if (pk[i] != 0xFFFFFFFFu) {
            int b = pk[i] >> 21;
            unsigned lt = (pk[i] >> 12) & (BNODES - 1);
            int l = pk[i] & 4095;
            ebuf[base[b] + l] = (lt << 23) | (unsigned)sv[i];
        }
    }
}

// ---- per-bucket CSR fill: LDS count + shfl scan + LDS cursor ----------------

__global__ __launch_bounds__(512) void k_bfill(const unsigned* __restrict__ ebuf,
                                               const int* __restrict__ gcur,
                                               int2* __restrict__ row,
                                               int* __restrict__ col,
                                               float* __restrict__ dinv, int n) {
    __shared__ int s_cnt[BNODES];
    __shared__ int s_cur[BNODES];
    __shared__ int wsum[8];
    int b = blockIdx.x, tid = threadIdx.x;
    int nbase = b << BSHIFT;
    int ebase = b << CAPSHIFT;
    int eend = gcur[b];
    s_cnt[tid] = 0;
    __syncthreads();
    for (int e = ebase + tid; e < eend; e += BNODES) {
        atomicAdd(&s_cnt[ebuf[e] >> 23], 1);
    }
    __syncthreads();
    int v = s_cnt[tid];
    int lane = tid & 63, wid = tid >> 6;
    int sc = v;
#pragma unroll
    for (int d = 1; d < 64; d <<= 1) {
        int t = __shfl_up(sc, d);
        if (lane >= d) sc += t;
    }
    if (lane == 63) wsum[wid] = sc;
    __syncthreads();
    int woff = 0;
#pragma unroll
    for (int i = 0; i < 8; i++) woff += (i < wid) ? wsum[i] : 0;
    int excl = sc + woff - v;
    s_cur[tid] = excl;
    int node = nbase + tid;
    if (node < n) {
        row[node] = make_int2(ebase + excl, ebase + excl + v);
        dinv[node] = rsqrtf((float)(v + 1));  // +1 self-loop
    }
    __syncthreads();
    for (int e = ebase + tid; e < eend; e += BNODES) {
        unsigned p = ebuf[e];
        int pos = atomicAdd(&s_cur[p >> 23], 1);
        col[ebase + pos] = (int)(p & 0x7FFFFFu);
    }
}

// ---- matmul 1 (MFMA): hs[n][j] = fp16((x[n] @ W1[:,j]) * dinv[n]) -----------
// 64 nodes x 64 cols per block; fp16 LDS tiles, pitch 136 (2-way bank = free).

__global__ __launch_bounds__(256) void k_mm1(const float* __restrict__ x,
                                             const float* __restrict__ W1,
                                             const float* __restrict__ dinv,
                                             __half* __restrict__ hs, int n) {
    __shared__ _Float16 xh[64 * 136];  // [node][k]
    __shared__ _Float16 Wt[64 * 136];  // [col][k] (transposed)
    int tid = threadIdx.x;
    int nbase = blockIdx.x * 64;
#pragma unroll
    for (int i = 0; i < 8; i++) {
        int f = tid + i * 256;  // 0..2047
        int r = f >> 5, c4 = f & 31;
        int node = nbase + r;
        float4 v = make_float4(0.f, 0.f, 0.f, 0.f);
        if (node < n) v = *(const float4*)(x + (size_t)node * 128 + c4 * 4);
        union { uint2 u; __half2 h[2]; } pk;
        pk.h[0] = __floats2half2_rn(v.x, v.y);
        pk.h[1] = __floats2half2_rn(v.z, v.w);
        *(uint2*)&xh[r * 136 + c4 * 4] = pk.u;
    }
#pragma unroll
    for (int i = 0; i < 16; i++) {
        int f = tid + i * 256;          // 0..4095
        int c = f & 63, kp = f >> 6;    // kp 0..63 (pairs of k)
        float a = W1[(size_t)(2 * kp) * 64 + c];
        float b = W1[(size_t)(2 * kp + 1) * 64 + c];
        *(__half2*)&Wt[c * 136 + 2 * kp] = __floats2half2_rn(a, b);
    }
    __syncthreads();
    int w = tid >> 6, lane = tid & 63;
    int quad = lane >> 4, m = lane & 15;
    floatx4 acc[4] = {{0.f, 0.f, 0.f, 0.f}, {0.f, 0.f, 0.f, 0.f},
                      {0.f, 0.f, 0.f, 0.f}, {0.f, 0.f, 0.f, 0.f}};
#pragma unroll
    for (int kt = 0; kt < 4; kt++) {
        half8 a = *(const half8*)&xh[(w * 16 + m) * 136 + kt * 32 + quad * 8];
#pragma unroll
        for (int ct = 0; ct < 4; ct++) {
            half8 b = *(const half8*)&Wt[(ct * 16 + m) * 136 + kt * 32 + quad * 8];
            acc[ct] = __builtin_amdgcn_mfma_f32_16x16x32_f16(a, b, acc[ct], 0, 0, 0);
        }
    }
#pragma unroll
    for (int reg = 0; reg < 4; reg++) {
        int node = nbase + w * 16 + quad * 4 + reg;
        if (node < n) {
            float d = dinv[node];
#pragma unroll
            for (int ct = 0; ct < 4; ct++) {
                hs[(size_t)node * 64 + ct * 16 + m] = __float2half(acc[ct][reg] * d);
            }
        }
    }
}

// ---- conv1: 4 nodes/wave (16-lane quarters), 8 feat lanes x 2 edge slots ----
// hs has a zeroed pad row at index n; invalid slots load it unconditionally.

__global__ __launch_bounds__(256) void k_conv1(const __half* __restrict__ hs,
                                               const int2* __restrict__ row,
                                               const int* __restrict__ col,
                                               const float* __restrict__ dinv,
                                               const float* __restrict__ b1,
                                               __half* __restrict__ h2, int n) {
    int gw = (blockIdx.x * 256 + threadIdx.x) >> 6;
    int lane = threadIdx.x & 63;
    int q = lane >> 4, ln = lane & 15;
    int w = gw * 4 + q;
    if (w >= n) return;  // whole quarter exits together
    int qb = q << 4;
    int el = ln >> 3, fl = ln & 7;  // 2 edge slots x 8 feat lanes
    int2 be = row[w];
    int beg = be.x, deg = be.y - be.x;
    int m = min(16, deg);
    int m2 = min(16, deg - 16);  // may be <=0
    int sl = (ln < m) ? col[beg + ln] : 0;
    int sl2 = (ln < m2) ? col[beg + 16 + ln] : 0;
    __half2 a2[4];
#pragma unroll
    for (int j = 0; j < 4; j++) a2[j] = __half2half2(__float2half(0.f));
    int rs = (el == 0) ? w : n;
    float4 S = *(const float4*)(hs + (size_t)rs * 64 + fl * 8);
    float4 L[4];
#pragma unroll
    for (int r = 0; r < 4; r++) {  // edges 0..7
        int idx = 2 * r + el;
        int s = __shfl(sl, qb + idx);
        int a = (idx < m) ? s : n;
        L[r] = *(const float4*)(hs + (size_t)a * 64 + fl * 8);
    }
    acc8(a2, S);
#pragma unroll
    for (int r = 0; r < 4; r++) acc8(a2, L[r]);
#pragma unroll
    for (int r = 0; r < 4; r++) {  // edges 8..15
        int idx = 8 + 2 * r + el;
        int s = __shfl(sl, qb + idx);
        int a = (idx < m) ? s : n;
        L[r] = *(const float4*)(hs + (size_t)a * 64 + fl * 8);
    }
#pragma unroll
    for (int r = 0; r < 4; r++) acc8(a2, L[r]);
    if (deg > 16) {  // edges 16..31 from sl2 (~43% of nodes)
#pragma unroll
        for (int r = 0; r < 4; r++) {
            int idx = 2 * r + el;
            int s = __shfl(sl2, qb + idx);
            int a = (idx < m2) ? s : n;
            L[r] = *(const float4*)(hs + (size_t)a * 64 + fl * 8);
        }
#pragma unroll
        for (int r = 0; r < 4; r++) acc8(a2, L[r]);
#pragma unroll
        for (int r = 0; r < 4; r++) {
            int idx = 8 + 2 * r + el;
            int s = __shfl(sl2, qb + idx);
            int a = (idx < m2) ? s : n;
            L[r] = *(const float4*)(hs + (size_t)a * 64 + fl * 8);
        }
#pragma unroll
        for (int r = 0; r < 4; r++) acc8(a2, L[r]);
    }
    if (deg > 32) {  // rare (~0.01%)
        for (int b0 = 32; b0 < deg; b0 += 16) {
            int mc = min(16, deg - b0);
            int sl3 = (ln < mc) ? col[beg + b0 + ln] : 0;
            for (int r = 0; r < 8; r++) {
                int idx = 2 * r + el;
                int s = __shfl(sl3, qb + idx);
                int a = (idx < mc) ? s : n;
                float4 v = *(const float4*)(hs + (size_t)a * 64 + fl * 8);
                acc8(a2, v);
            }
        }
    }
    float r[8];
#pragma unroll
    for (int j = 0; j < 4; j++) {
        float2 f = __half22float2(a2[j]);
        r[2 * j] = f.x;
        r[2 * j + 1] = f.y;
    }
#pragma unroll
    for (int j = 0; j < 8; j++) r[j] += __shfl_xor(r[j], 8);

    if (el == 0) {
        float d = dinv[w];
        float4 bb0 = *(const float4*)(b1 + fl * 8);
        float4 bb1 = *(const float4*)(b1 + fl * 8 + 4);
        union { float4 f; __half2 h[4]; } u;
        u.h[0] = __floats2half2_rn(fmaxf(r[0] * d + bb0.x, 0.f),
                                   fmaxf(r[1] * d + bb0.y, 0.f));
        u.h[1] = __floats2half2_rn(fmaxf(r[2] * d + bb0.z, 0.f),
                                   fmaxf(r[3] * d + bb0.w, 0.f));
        u.h[2] = __floats2half2_rn(fmaxf(r[4] * d + bb1.x, 0.f),
                                   fmaxf(r[5] * d + bb1.y, 0.f));
        u.h[3] = __floats2half2_rn(fmaxf(r[6] * d + bb1.z, 0.f),
                                   fmaxf(r[7] * d + bb1.w, 0.f));
        *(float4*)(h2 + (size_t)w * 64 + fl * 8) = u.f;
    }
}

// ---- matmul 2 (MFMA): zs[n][c] = fp16((h2[n] @ W2[:,c]) * dinv[n]) ----------

__global__ __launch_bounds__(256) void k_mm2(const __half* __restrict__ h2,
                                             const float* __restrict__ W2,
                                             const float* __restrict__ dinv,
                                             __half* __restrict__ zs, int n) {
    __shared__ _Float16 Wt[32 * 72];  // [col][k] (transposed)
    int tid = threadIdx.x;
    int nbase = blockIdx.x * 64;
#pragma unroll
    for (int i = 0; i < 4; i++) {
        int f = tid + i * 256;          // 0..1023
        int c = f & 31, kp = f >> 5;    // kp 0..31
        float a = W2[(size_t)(2 * kp) * 32 + c];
        float b = W2[(size_t)(2 * kp + 1) * 32 + c];
        *(__half2*)&Wt[c * 72 + 2 * kp] = __floats2half2_rn(a, b);
    }
    __syncthreads();
    int w = tid >> 6, lane = tid & 63;
    int quad = lane >> 4, m = lane & 15;
    int arow = nbase + w * 16 + m;
    const __half* abase = h2 + (size_t)min(arow, n - 1) * 64;  // clamped rows
    floatx4 acc[2] = {{0.f, 0.f, 0.f, 0.f}, {0.f, 0.f, 0.f, 0.f}};
#pragma unroll
    for (int kt = 0; kt < 2; kt++) {
        half8 a = *(const half8*)(abase + kt * 32 + quad * 8);
#pragma unroll
        for (int ct = 0; ct < 2; ct++) {
            half8 b = *(const half8*)&Wt[(ct * 16 + m) * 72 + kt * 32 + quad * 8];
            acc[ct] = __builtin_amdgcn_mfma_f32_16x16x32_f16(a, b, acc[ct], 0, 0, 0);
        }
    }
#pragma unroll
    for (int reg = 0; reg < 4; reg++) {
        int node = nbase + w * 16 + quad * 4 + reg;
        if (node < n) {
            float d = dinv[node];
#pragma unroll
            for (int ct = 0; ct < 2; ct++) {
                zs[(size_t)node * 32 + ct * 16 + m] = __float2half(acc[ct][reg] * d);
            }
        }
    }
}

// ---- conv2: 4 nodes/wave (16-lane quarters), 4 feat lanes x 4 edge slots ----
// zs has a zeroed pad row at index n. bf16 zh epilogue for decode.

__global__ __launch_bounds__(256) void k_conv2(const __half* __restrict__ zs,
                                               const int2* __restrict__ row,
                                               const int* __restrict__ col,
                                               const float* __restrict__ dinv,
                                               const float* __restrict__ b2,
                                               float* __restrict__ zout,
                                               unsigned short* __restrict__ zh, int n) {
    int gw = (blockIdx.x * 256 + threadIdx.x) >> 6;
    int lane = threadIdx.x & 63;
    int q = lane >> 4, ln = lane & 15;
    int w = gw * 4 + q;
    if (w >= n) return;
    int qb = q << 4;
    int el = ln >> 2, fl = ln & 3;  // 4 edge slots x 4 feat lanes
    int2 be = row[w];
    int beg = be.x, deg = be.y - be.x;
    int m = min(16, deg);
    int m2 = min(16, deg - 16);
    int sl = (ln < m) ? col[beg + ln] : 0;
    int sl2 = (ln < m2) ? col[beg + 16 + ln] : 0;
    __half2 a2[4];
#pragma unroll
    for (int j = 0; j < 4; j++) a2[j] = __half2half2(__float2half(0.f));
    int rs = (el == 0) ? w : n;
    float4 S = *(const float4*)(zs + (size_t)rs * 32 + fl * 8);
    float4 L[4];
#pragma unroll
    for (int r = 0; r < 4; r++) {  // edges 0..15
        int idx = 4 * r + el;
        int s = __shfl(sl, qb + idx);
        int a = (idx < m) ? s : n;
        L[r] = *(const float4*)(zs + (size_t)a * 32 + fl * 8);
    }
    acc8(a2, S);
#pragma unroll
    for (int r = 0; r < 4; r++) acc8(a2, L[r]);
    if (deg > 16) {  // edges 16..31
#pragma unroll
        for (int r = 0; r < 4; r++) {
            int idx = 4 * r + el;
            int s = __shfl(sl2, qb + idx);
            int a = (idx < m2) ? s : n;
            L[r] = *(const float4*)(zs + (size_t)a * 32 + fl * 8);
        }
#pragma unroll
        for (int r = 0; r < 4; r++) acc8(a2, L[r]);
    }
    if (deg > 32) {  // rare
        for (int b0 = 32; b0 < deg; b0 += 16) {
            int mc = min(16, deg - b0);
            int sl3 = (ln < mc) ? col[beg + b0 + ln] : 0;
            for (int r = 0; r < 4; r++) {
                int idx = 4 * r + el;
                int s = __shfl(sl3, qb + idx);
                int a = (idx < mc) ? s : n;
                float4 v = *(const float4*)(zs + (size_t)a * 32 + fl * 8);
                acc8(a2, v);
            }
        }
    }
    float r[8];
#pragma unroll
    for (int j = 0; j < 4; j++) {
        float2 f = __half22float2(a2[j]);
        r[2 * j] = f.x;
        r[2 * j + 1] = f.y;
    }
#pragma unroll
    for (int d = 4; d < 16; d <<= 1)
#pragma unroll
        for (int j = 0; j < 8; j++) r[j] += __shfl_xor(r[j], d);

    if (el == 0) {  // lanes fl=0..3 of each quarter, 8 feats each
        float d = dinv[w];
        float4 bb0 = *(const float4*)(b2 + fl * 8);
        float4 bb1 = *(const float4*)(b2 + fl * 8 + 4);
        float o0 = r[0] * d + bb0.x, o1 = r[1] * d + bb0.y;
        float o2 = r[2] * d + bb0.z, o3 = r[3] * d + bb0.w;
        float o4 = r[4] * d + bb1.x, o5 = r[5] * d + bb1.y;
        float o6 = r[6] * d + bb1.z, o7 = r[7] * d + bb1.w;
        *(float4*)(zout + (size_t)w * 32 + fl * 8) = make_float4(o0, o1, o2, o3);
        *(float4*)(zout + (size_t)w * 32 + fl * 8 + 4) = make_float4(o4, o5, o6, o7);
        uint4 p;
        p.x = (unsigned)f2bf(o0) | ((unsigned)f2bf(o1) << 16);
        p.y = (unsigned)f2bf(o2) | ((unsigned)f2bf(o3) << 16);
        p.z = (unsigned)f2bf(o4) | ((unsigned)f2bf(o5) << 16);
        p.w = (unsigned)f2bf(o6) | ((unsigned)f2bf(o7) << 16);
        *(uint4*)(zh + (size_t)w * 32 + fl * 8) = p;
    }
}

// ---- decode: bf16 rows (64B), 2 lanes/edge (32B each), 32 edges/wave --------

__device__ inline float bfdot8(uint4 a, uint4 b) {
    const unsigned* pa = (const unsigned*)&a;
    const unsigned* pb = (const unsigned*)&b;
    float v = 0.f;
#pragma unroll
    for (int w = 0; w < 4; w++) {
        float alo = __builtin_bit_cast(float, pa[w] << 16);
        float ahi = __builtin_bit_cast(float, pa[w] & 0xFFFF0000u);
        float blo = __builtin_bit_cast(float, pb[w] << 16);
        float bhi = __builtin_bit_cast(float, pb[w] & 0xFFFF0000u);
        v += alo * blo + ahi * bhi;
    }
    return v;
}

__global__ __launch_bounds__(256) void k_decode(const unsigned short* __restrict__ zh,
                                                const int* __restrict__ src,
                                                const int* __restrict__ tgt,
                                                float* __restrict__ recon, int E) {
    int e = (blockIdx.x * 256 + threadIdx.x) >> 1;
    if (e >= E) return;
    int hl = threadIdx.x & 1;  // which 32B half of the row
    int s = src[e], t = tgt[e];
    const uint4* za = (const uint4*)(zh + (size_t)s * 32 + hl * 16);
    const uint4* zb = (const uint4*)(zh + (size_t)t * 32 + hl * 16);
    uint4 a0 = za[0], b0 = zb[0];
    uint4 a1 = za[1], b1 = zb[1];
    float v = bfdot8(a0, b0) + bfdot8(a1, b1);
    v += __shfl_xor(v, 1);
    if (hl == 0) recon[e] = v;
}

extern "C" void kernel_launch(void* const* d_in, const int* in_sizes, int n_in,
                              void* d_out, int out_size, void* d_ws, size_t ws_size,
                              hipStream_t stream) {
    const float* x = (const float*)d_in[0];
    const float* W1 = (const float*)d_in[1];
    const float* b1 = (const float*)d_in[2];
    const float* W2 = (const float*)d_in[3];
    const float* b2 = (const float*)d_in[4];
    const int* ei = (const int*)d_in[5];

    int N = in_sizes[0] / 128;
    int E = in_sizes[5] / 2;
    const int* src = ei;
    const int* tgt = ei + E;
    int NB = divup(N, BNODES);

    char* ws = (char*)d_ws;
    size_t off = 0;
    auto alloc = [&](size_t bytes) {
        size_t r = off;
        off += (bytes + 255) & ~(size_t)255;
        return r;
    };
    int* gcur = (int*)(ws + alloc(NBMAX * 4));
    unsigned* ebuf = (unsigned*)(ws + alloc((size_t)NB * CAP * 4));
    int* col = (int*)(ws + alloc((size_t)NB * CAP * 4));
    int2* row = (int2*)(ws + alloc((size_t)N * 8));
    float* dinv = (float*)(ws + alloc((size_t)N * 4));
    __half* hs = (__half*)(ws + alloc((size_t)(N + 1) * 64 * 2));   // +pad row n
    __half* h2 = (__half*)(ws + alloc((size_t)N * 64 * 2));
    __half* zs = (__half*)(ws + alloc((size_t)(N + 1) * 32 * 2));   // +pad row n
    unsigned short* zh = (unsigned short*)(ws + alloc((size_t)N * 32 * 2));

    float* zout = (float*)d_out;
    float* recon = zout + (size_t)N * 32;

    k_init<<<1, 256, 0, stream>>>(gcur, (unsigned*)(hs + (size_t)N * 64),
                                  (unsigned*)(zs + (size_t)N * 32));
    k_part<<<divup(E, CH), 256, 0, stream>>>(src, tgt, gcur, ebuf, E, NB);
    k_bfill<<<NB, BNODES, 0, stream>>>(ebuf, gcur, row, col, dinv, N);

    k_mm1<<<divup(N, 64), 256, 0, stream>>>(x, W1, dinv, hs, N);
    k_conv1<<<divup(N, 16), 256, 0, stream>>>(hs, row, col, dinv, b1, h2, N);
    k_mm2<<<divup(N, 64), 256, 0, stream>>>(h2, W2, dinv, zs, N);
    k_conv2<<<divup(N, 16), 256, 0, stream>>>(zs, row, col, dinv, b2, zout, zh, N);
    k_decode<<<divup(E, 128), 256, 0, stream>>>(zh, src, tgt, recon, E);
}